// Round 4
// baseline (142.311 us; speedup 1.0000x reference)
//
#include <hip/hip_runtime.h>
#include <math.h>

#define NSUB   2048
#define NTRIAL 40
#define NPATH  12341
#define PBLK   1024
#define NFULL  (NPATH / PBLK)          // 12 full iterations (12288 paths)
#define NTAIL  (NPATH - NFULL * PBLK)  // 53 remainder paths
#define SPB    8                       // subjects per persistent block
#define NBLK   (NSUB / SPB)            // 256 blocks = 1 per CU

#define LOG2E  1.44269504088896340736f

// ---------------------------------------------------------------------------
// Kernel 1: per-path decode. Monotone path -> packed breakpoints
// (t1,t2,t3) = counts of trials in states <=0, <=1, <=2, and log2 P(path).
// Record: int2 { float log2p (bitcast), int bp }.
// ---------------------------------------------------------------------------
__global__ __launch_bounds__(64) void path_kernel(
        const int* __restrict__ paths,
        const float* __restrict__ w_sp,
        const float* __restrict__ w_tr,
        int2* __restrict__ rec) {
    __shared__ float sprior[4];
    __shared__ float str[16];
    const int tid = threadIdx.x;

    if (tid < 4) {
        float m = fmaxf(fmaxf(w_sp[0], w_sp[1]), fmaxf(w_sp[2], w_sp[3]));
        float s = 0.f;
        for (int k = 0; k < 4; k++) s += __expf(w_sp[k] - m);
        sprior[tid] = (w_sp[tid] - (__logf(s) + m)) * LOG2E;
    } else if (tid < 20) {
        int idx = tid - 4, i = idx >> 2, j = idx & 3;
        float m = -1e30f;
        for (int k = i; k < 4; k++) m = fmaxf(m, w_tr[i*4 + k]);
        float s = 0.f;
        for (int k = i; k < 4; k++) s += __expf(w_tr[i*4 + k] - m);
        str[idx] = (j >= i) ? (w_tr[i*4 + j] - (__logf(s) + m)) * LOG2E : 0.f;
    }
    __syncthreads();

    int p = blockIdx.x * 64 + tid;
    if (p >= NPATH) return;

    const int4* pp = (const int4*)(paths + (size_t)p * NTRIAL);
    int st[NTRIAL];
#pragma unroll
    for (int q = 0; q < NTRIAL / 4; q++) {
        int4 v = pp[q];
        st[4*q] = v.x; st[4*q+1] = v.y; st[4*q+2] = v.z; st[4*q+3] = v.w;
    }
    float lp = sprior[st[0]];
    int c0 = (st[0] == 0), c1 = (st[0] <= 1), c2 = (st[0] <= 2);
#pragma unroll
    for (int t = 1; t < NTRIAL; t++) {
        lp += str[st[t-1]*4 + st[t]];
        c0 += (st[t] == 0); c1 += (st[t] <= 1); c2 += (st[t] <= 2);
    }
    rec[p] = make_int2(__float_as_int(lp), c0 | (c1 << 6) | (c2 << 12));
}

// ---------------------------------------------------------------------------
// Kernel 2: PERSISTENT blocks — 256 blocks (1/CU), each handles 8 subjects.
//   - rec records loaded ONCE into registers, reused for all 8 subjects
//     (rec L2 traffic 202 MB -> 25 MB; 12-deep load latency paid once).
//   - lsr is subject-independent: computed once per block.
//   - All 8 subjects' D-tables + CT3 built in ONE wave-parallel phase
//     (32 wave-tasks across 16 waves), one barrier.
//   - Per subject: 12x {3 LDS gathers + exp2}, 2 barriers for the sum,
//     nontemporal stores. Zero global reads in the subject loop.
// __launch_bounds__(1024,4): VGPR cap 128 (live ~75, no spill).
// ---------------------------------------------------------------------------
__global__ __launch_bounds__(1024, 4) void post_kernel(
        const int* __restrict__ resp,
        const float* __restrict__ w_ss,
        const int2* __restrict__ rec,
        float* __restrict__ out) {
    __shared__ float lsr[16];              // log2 p_state_responses
    __shared__ int   rs[SPB * NTRIAL];     // 8 subjects' responses (flat)
    __shared__ float D[SPB][3][NTRIAL + 1];
    __shared__ float red[16];
    __shared__ float s_inv;
    __shared__ float s_ct3[SPB];

    const int tid  = threadIdx.x;
    const int lane = tid & 63, wave = tid >> 6;
    const int sbase = blockIdx.x * SPB;

    // ---- rec loads: once per block, reused across all SPB subjects ----
    float lp[NFULL]; int bp[NFULL];
#pragma unroll
    for (int i = 0; i < NFULL; i++) {
        int2 rr = rec[tid + PBLK * i];
        lp[i] = __int_as_float(rr.x); bp[i] = rr.y;
    }
    const bool tail = (tid < NTAIL);
    float lpt = 0.f; int bpt = 0;
    if (tail) {
        int2 rr = rec[NFULL * PBLK + tid];
        lpt = __int_as_float(rr.x); bpt = rr.y;
    }

    // ---- all 8 subjects' responses (320 ints), lsr on a high wave ----
    if (tid < SPB * NTRIAL)
        rs[tid] = resp[(size_t)sbase * NTRIAL + tid];
    if (wave == 15 && lane < 16) {
        const float psr[4][4] = {
            {3.f/9.f, 4.f/9.f, 1.f/9.f, 1.f/9.f},
            {0.f,     4.f/6.f, 1.f/6.f, 1.f/6.f},
            {0.f,     0.f,     0.5f,    0.5f},
            {0.f,     0.f,     0.f,     1.f}};
        int i = lane >> 2, rr = lane & 3;
        float m = -1e30f;
        for (int j = 0; j <= i; j++) m = fmaxf(m, w_ss[i*4 + j]);
        float e[4] = {0.f,0.f,0.f,0.f}, ssum = 0.f;
        for (int j = 0; j <= i; j++) { e[j] = __expf(w_ss[i*4 + j] - m); ssum += e[j]; }
        float acc = 0.f;
        for (int j = 0; j <= i; j++) acc += (e[j] / ssum) * psr[j][rr];
        lsr[lane] = __builtin_amdgcn_logf(acc);   // log2
    }
    __syncthreads();

    // ---- one wave-parallel phase: 8 subjects x (3 scans + CT3) = 32 tasks ----
#pragma unroll
    for (int task = wave; task < 4 * SPB; task += 16) {
        const int su = task >> 2, role = task & 3;
        if (role < 3) {
            float x = 0.f;
            if (lane < NTRIAL) {
                int rv = rs[su * NTRIAL + lane];
                x = lsr[role*4 + rv] - lsr[role*4 + 4 + rv];
            }
#pragma unroll
            for (int off = 1; off < 64; off <<= 1) {
                float y = __shfl_up(x, off, 64);
                if (lane >= off) x += y;
            }
            if (lane < NTRIAL) D[su][role][lane + 1] = x;
            if (lane == 0)     D[su][role][0] = 0.f;
        } else {
            float t = (lane < NTRIAL) ? lsr[12 + rs[su * NTRIAL + lane]] : 0.f;
#pragma unroll
            for (int off = 32; off > 0; off >>= 1)
                t += __shfl_down(t, off, 64);
            if (lane == 0) s_ct3[su] = t;
        }
    }
    __syncthreads();

    // ---- subject loop: zero global reads, 2 barriers per subject ----
    for (int su = 0; su < SPB; su++) {
        const float ct3 = s_ct3[su];
        const float* __restrict__ D1 = D[su][0];
        const float* __restrict__ D2 = D[su][1];
        const float* __restrict__ D3 = D[su][2];

        float nums[NFULL];
        float lsum = 0.f;
#pragma unroll
        for (int i = 0; i < NFULL; i++) {
            int b = bp[i];
            float v = __builtin_amdgcn_exp2f(
                lp[i] + ct3 + D1[b & 63] + D2[(b >> 6) & 63] + D3[(b >> 12) & 63]);
            nums[i] = v;
            lsum += v;
        }
        float numt = 0.f;
        if (tail) {
            int b = bpt;
            numt = __builtin_amdgcn_exp2f(
                lpt + ct3 + D1[b & 63] + D2[(b >> 6) & 63] + D3[(b >> 12) & 63]);
            lsum += numt;
        }

#pragma unroll
        for (int off = 32; off > 0; off >>= 1)
            lsum += __shfl_down(lsum, off, 64);
        if (lane == 0) red[wave] = lsum;
        __syncthreads();
        if (tid < 64) {
            float t = (lane < 16) ? red[lane] : 0.f;
#pragma unroll
            for (int off = 8; off > 0; off >>= 1)
                t += __shfl_down(t, off, 64);
            if (lane == 0) s_inv = 1.f / t;
        }
        __syncthreads();
        const float inv = s_inv;

        float* orow = out + (size_t)(sbase + su) * NPATH;
#pragma unroll
        for (int i = 0; i < NFULL; i++)
            __builtin_nontemporal_store(nums[i] * inv, &orow[tid + PBLK * i]);
        if (tail)
            __builtin_nontemporal_store(numt * inv, &orow[NFULL * PBLK + tid]);
    }
}

// ---------------------------------------------------------------------------
extern "C" void kernel_launch(void* const* d_in, const int* in_sizes, int n_in,
                              void* d_out, int out_size, void* d_ws, size_t ws_size,
                              hipStream_t stream) {
    const int*   resp  = (const int*)d_in[0];
    const int*   paths = (const int*)d_in[1];
    const float* w_ss  = (const float*)d_in[2];
    const float* w_sp  = (const float*)d_in[3];
    const float* w_tr  = (const float*)d_in[4];
    float* out = (float*)d_out;

    int2* rec = (int2*)d_ws;   // NPATH records (8 B each)

    path_kernel<<<(NPATH + 63) / 64, 64, 0, stream>>>(paths, w_sp, w_tr, rec);
    post_kernel<<<NBLK, PBLK, 0, stream>>>(resp, w_ss, rec, out);
}

// Round 5
// 137.103 us; speedup vs baseline: 1.0380x; 1.0380x over previous
//
#include <hip/hip_runtime.h>
#include <math.h>

#define NSUB   2048
#define NTRIAL 40
#define NPATH  12341
#define PBLK   1024
#define NFULL  (NPATH / PBLK)          // 12 full iterations (12288 paths)
#define NTAIL  (NPATH - NFULL * PBLK)  // 53 remainder paths

#define LOG2E  1.44269504088896340736f

// ---------------------------------------------------------------------------
// Kernel 1: per-path decode. Monotone path -> packed breakpoints
// (t1,t2,t3) = counts of trials in states <=0, <=1, <=2, and log2 P(path).
// Record: int2 { float log2p (bitcast), int bp }.
// ---------------------------------------------------------------------------
__global__ __launch_bounds__(64) void path_kernel(
        const int* __restrict__ paths,
        const float* __restrict__ w_sp,
        const float* __restrict__ w_tr,
        int2* __restrict__ rec) {
    __shared__ float sprior[4];
    __shared__ float str[16];
    const int tid = threadIdx.x;

    if (tid < 4) {
        float m = fmaxf(fmaxf(w_sp[0], w_sp[1]), fmaxf(w_sp[2], w_sp[3]));
        float s = 0.f;
        for (int k = 0; k < 4; k++) s += __expf(w_sp[k] - m);
        sprior[tid] = (w_sp[tid] - (__logf(s) + m)) * LOG2E;
    } else if (tid < 20) {
        int idx = tid - 4, i = idx >> 2, j = idx & 3;
        float m = -1e30f;
        for (int k = i; k < 4; k++) m = fmaxf(m, w_tr[i*4 + k]);
        float s = 0.f;
        for (int k = i; k < 4; k++) s += __expf(w_tr[i*4 + k] - m);
        str[idx] = (j >= i) ? (w_tr[i*4 + j] - (__logf(s) + m)) * LOG2E : 0.f;
    }
    __syncthreads();

    int p = blockIdx.x * 64 + tid;
    if (p >= NPATH) return;

    const int4* pp = (const int4*)(paths + (size_t)p * NTRIAL);
    int st[NTRIAL];
#pragma unroll
    for (int q = 0; q < NTRIAL / 4; q++) {
        int4 v = pp[q];
        st[4*q] = v.x; st[4*q+1] = v.y; st[4*q+2] = v.z; st[4*q+3] = v.w;
    }
    float lp = sprior[st[0]];
    int c0 = (st[0] == 0), c1 = (st[0] <= 1), c2 = (st[0] <= 2);
#pragma unroll
    for (int t = 1; t < NTRIAL; t++) {
        lp += str[st[t-1]*4 + st[t]];
        c0 += (st[t] == 0); c1 += (st[t] <= 1); c2 += (st[t] <= 2);
    }
    rec[p] = make_int2(__float_as_int(lp), c0 | (c1 << 6) | (c2 << 12));
}

// ---------------------------------------------------------------------------
// Kernel 2: one block (1024 thr) per subject.  (Best-measured variant, R1,
// 136.9 us, + CT3 re-centering from R2/R3 for accuracy.)
// log2-numerator(p) = log2p + D1[t1] + D2[t2] + D3[t3] + CT3
//   D1[t]=C0[t]-C1[t], D2[t]=C1[t]-C2[t], D3[t]=C2[t]-C3[t], CT3=C3[40].
// D tables via wave-parallel shuffle difference-scans; CT3 by wave 3
// (otherwise idle) via shuffle reduce, folded as a uniform add in the
// exponent. rec loads hoisted for MLP. No launch-bounds cap (R2 showed the
// 64-VGPR cap spills against r[12]+nums[12]).
// ---------------------------------------------------------------------------
__global__ __launch_bounds__(1024) void post_kernel(
        const int* __restrict__ resp,
        const float* __restrict__ w_ss,
        const int2* __restrict__ rec,
        float* __restrict__ out) {
    __shared__ float lsr[16];            // log2 p_state_responses
    __shared__ int   rs[NTRIAL];
    __shared__ float D1[NTRIAL + 1], D2[NTRIAL + 1], D3[NTRIAL + 1];
    __shared__ float red[16];
    __shared__ float s_inv;
    __shared__ float s_ct3;

    const int s = blockIdx.x;
    const int tid = threadIdx.x;
    const int lane = tid & 63, wave = tid >> 6;

    // wave 3 loads responses while wave 0 computes lsr — overlapped
    if (wave == 3 && lane < NTRIAL)
        rs[lane] = resp[(size_t)s * NTRIAL + lane];
    if (tid < 16) {
        const float psr[4][4] = {
            {3.f/9.f, 4.f/9.f, 1.f/9.f, 1.f/9.f},
            {0.f,     4.f/6.f, 1.f/6.f, 1.f/6.f},
            {0.f,     0.f,     0.5f,    0.5f},
            {0.f,     0.f,     0.f,     1.f}};
        int i = tid >> 2, r = tid & 3;
        float m = -1e30f;
        for (int j = 0; j <= i; j++) m = fmaxf(m, w_ss[i*4 + j]);
        float e[4] = {0.f,0.f,0.f,0.f}, ssum = 0.f;
        for (int j = 0; j <= i; j++) { e[j] = __expf(w_ss[i*4 + j] - m); ssum += e[j]; }
        float acc = 0.f;
        for (int j = 0; j <= i; j++) acc += (e[j] / ssum) * psr[j][r];
        lsr[tid] = __builtin_amdgcn_logf(acc);   // log2
    }
    __syncthreads();

    // waves 0..2: D_{w+1}[t] = prefix-scan of (lsr[w][r_t] - lsr[w+1][r_t])
    // wave 3: CT3 = sum_t lsr[3][r_t]  (shuffle reduce)
    if (wave < 3) {
        float x = 0.f;
        if (lane < NTRIAL) {
            int rv = rs[lane];
            x = lsr[wave*4 + rv] - lsr[wave*4 + 4 + rv];
        }
#pragma unroll
        for (int off = 1; off < 64; off <<= 1) {
            float y = __shfl_up(x, off, 64);
            if (lane >= off) x += y;
        }
        float* D = (wave == 0) ? D1 : (wave == 1) ? D2 : D3;
        if (lane < NTRIAL) D[lane + 1] = x;
        if (lane == 0)     D[0] = 0.f;
    } else if (wave == 3) {
        float t = (lane < NTRIAL) ? lsr[12 + rs[lane]] : 0.f;
#pragma unroll
        for (int off = 32; off > 0; off >>= 1)
            t += __shfl_down(t, off, 64);
        if (lane == 0) s_ct3 = t;
    }
    __syncthreads();

    // ---- load all rec records up front (12 outstanding dwordx2 + tail) ----
    int2 r[NFULL];
#pragma unroll
    for (int i = 0; i < NFULL; i++) r[i] = rec[tid + PBLK * i];
    const bool tail = (tid < NTAIL);
    int2 rt = tail ? rec[NFULL * PBLK + tid] : make_int2(0, 0);

    const float ct3 = s_ct3;
    float nums[NFULL];
    float lsum = 0.f;
#pragma unroll
    for (int i = 0; i < NFULL; i++) {
        int b = r[i].y;
        int t1 = b & 63, t2 = (b >> 6) & 63, t3 = (b >> 12) & 63;
        float v = __builtin_amdgcn_exp2f(
            __int_as_float(r[i].x) + ct3 + D1[t1] + D2[t2] + D3[t3]);
        nums[i] = v;
        lsum += v;
    }
    float numt = 0.f;
    if (tail) {
        int b = rt.y;
        int t1 = b & 63, t2 = (b >> 6) & 63, t3 = (b >> 12) & 63;
        numt = __builtin_amdgcn_exp2f(
            __int_as_float(rt.x) + ct3 + D1[t1] + D2[t2] + D3[t3]);
        lsum += numt;
    }

    // wave64 shuffle reduce, then cross-wave (wave-parallel)
#pragma unroll
    for (int off = 32; off > 0; off >>= 1)
        lsum += __shfl_down(lsum, off, 64);
    if (lane == 0) red[wave] = lsum;
    __syncthreads();
    if (tid < 64) {
        float t = (lane < 16) ? red[lane] : 0.f;
#pragma unroll
        for (int off = 8; off > 0; off >>= 1)
            t += __shfl_down(t, off, 64);
        if (lane == 0) s_inv = 1.f / t;
    }
    __syncthreads();
    const float inv = s_inv;

    float* orow = out + (size_t)s * NPATH;
#pragma unroll
    for (int i = 0; i < NFULL; i++)
        __builtin_nontemporal_store(nums[i] * inv, &orow[tid + PBLK * i]);
    if (tail)
        __builtin_nontemporal_store(numt * inv, &orow[NFULL * PBLK + tid]);
}

// ---------------------------------------------------------------------------
extern "C" void kernel_launch(void* const* d_in, const int* in_sizes, int n_in,
                              void* d_out, int out_size, void* d_ws, size_t ws_size,
                              hipStream_t stream) {
    const int*   resp  = (const int*)d_in[0];
    const int*   paths = (const int*)d_in[1];
    const float* w_ss  = (const float*)d_in[2];
    const float* w_sp  = (const float*)d_in[3];
    const float* w_tr  = (const float*)d_in[4];
    float* out = (float*)d_out;

    int2* rec = (int2*)d_ws;   // NPATH records (8 B each)

    path_kernel<<<(NPATH + 63) / 64, 64, 0, stream>>>(paths, w_sp, w_tr, rec);
    post_kernel<<<NSUB, PBLK, 0, stream>>>(resp, w_ss, rec, out);
}